// Round 7
// baseline (25399.815 us; speedup 1.0000x reference)
//
#include <hip/hip_runtime.h>
#include <stdint.h>

#define B_SZ 32768
#define D_SZ 16
#define HALF_SZ 8
#define IN_DIM 11
#define H_SZ 2048
#define NLAYERS 6
#define ROWS 8
#define NTHREADS 256

// ---------------- threefry2x32-20, generic key ----------------
__device__ __forceinline__ uint32_t rotl32(uint32_t v, int n) {
    return (v << n) | (v >> (32 - n));
}

__device__ __forceinline__ void threefry2x32(uint32_t k0, uint32_t k1,
                                             uint32_t c0, uint32_t c1,
                                             uint32_t& o0, uint32_t& o1) {
    const uint32_t k2 = k0 ^ k1 ^ 0x1BD11BDAu;
    uint32_t x0 = c0 + k0, x1 = c1 + k1;
    // rounds 1-4 (A = 13,15,26,6)
    x0 += x1; x1 = rotl32(x1, 13); x1 ^= x0;
    x0 += x1; x1 = rotl32(x1, 15); x1 ^= x0;
    x0 += x1; x1 = rotl32(x1, 26); x1 ^= x0;
    x0 += x1; x1 = rotl32(x1,  6); x1 ^= x0;
    x0 += k1; x1 += k2 + 1u;
    // rounds 5-8 (B = 17,29,16,24)
    x0 += x1; x1 = rotl32(x1, 17); x1 ^= x0;
    x0 += x1; x1 = rotl32(x1, 29); x1 ^= x0;
    x0 += x1; x1 = rotl32(x1, 16); x1 ^= x0;
    x0 += x1; x1 = rotl32(x1, 24); x1 ^= x0;
    x0 += k2; x1 += k0 + 2u;
    // rounds 9-12 (A)
    x0 += x1; x1 = rotl32(x1, 13); x1 ^= x0;
    x0 += x1; x1 = rotl32(x1, 15); x1 ^= x0;
    x0 += x1; x1 = rotl32(x1, 26); x1 ^= x0;
    x0 += x1; x1 = rotl32(x1,  6); x1 ^= x0;
    x0 += k0; x1 += k1 + 3u;
    // rounds 13-16 (B)
    x0 += x1; x1 = rotl32(x1, 17); x1 ^= x0;
    x0 += x1; x1 = rotl32(x1, 29); x1 ^= x0;
    x0 += x1; x1 = rotl32(x1, 16); x1 ^= x0;
    x0 += x1; x1 = rotl32(x1, 24); x1 ^= x0;
    x0 += k1; x1 += k2 + 4u;
    // rounds 17-20 (A)
    x0 += x1; x1 = rotl32(x1, 13); x1 ^= x0;
    x0 += x1; x1 = rotl32(x1, 15); x1 ^= x0;
    x0 += x1; x1 = rotl32(x1, 26); x1 ^= x0;
    x0 += x1; x1 = rotl32(x1,  6); x1 ^= x0;
    x0 += k2; x1 += k0 + 5u;
    o0 = x0; o1 = x1;
}

// noise[m] for jax.random.normal(key(42),(6,B,11))*0.05 under
// jax_threefry_partitionable=True: per-element uint64 counter ->
// counter words (m>>32, m&0xffffffff) = (0, m); 32-bit draw = bits1 ^ bits2.
__device__ float noise_at(uint32_t m) {
    uint32_t o0, o1;
    threefry2x32(0u, 42u, 0u, m, o0, o1);
    uint32_t bits = o0 ^ o1;  // VARIANT: partitionable-xor (jax _threefry_random_bits_partitionable)
    float f = __uint_as_float((bits >> 9) | 0x3f800000u) - 1.0f;
    float u = fmaf(f, 2.0f, -0.99999994f);
    u = fmaxf(-0.99999994f, u);
    // XLA ErfInv32 (Giles)
    float w = -log1pf(-u * u);
    float p;
    if (w < 5.0f) {
        w = w - 2.5f;
        p = 2.81022636e-08f;
        p = fmaf(p, w, 3.43273939e-07f);
        p = fmaf(p, w, -3.5233877e-06f);
        p = fmaf(p, w, -4.39150654e-06f);
        p = fmaf(p, w, 0.00021858087f);
        p = fmaf(p, w, -0.00125372503f);
        p = fmaf(p, w, -0.00417768164f);
        p = fmaf(p, w, 0.246640727f);
        p = fmaf(p, w, 1.50140941f);
    } else {
        w = sqrtf(w) - 3.0f;
        p = -0.000200214257f;
        p = fmaf(p, w, 0.000100950558f);
        p = fmaf(p, w, 0.00134934322f);
        p = fmaf(p, w, -0.00367342844f);
        p = fmaf(p, w, 0.00573950773f);
        p = fmaf(p, w, -0.0076224613f);
        p = fmaf(p, w, 0.00943887047f);
        p = fmaf(p, w, 1.00167406f);
        p = fmaf(p, w, 2.83297682f);
    }
    float nrm = 1.4142135623730951f * (p * u);
    return nrm * 0.05f;
}

// ---------------- numpy SeedSequence -> PCG64 ----------------
struct PCG128 {
    __uint128_t state, inc;
    uint32_t ubuf; int has;

    __device__ void init(uint32_t entropy) {
        uint32_t pool[4];
        uint32_t hc = 0x43b0d7e5u;  // INIT_A
        auto hashmix = [&hc](uint32_t val) {
            val ^= hc;
            hc *= 0x931e8875u;  // MULT_A
            val *= hc;
            val ^= val >> 16;
            return val;
        };
        auto mixfn = [](uint32_t x, uint32_t y) {
            uint32_t r = x * 0xca01f9ddu - y * 0x4973f715u;
            r ^= r >> 16;
            return r;
        };
        pool[0] = hashmix(entropy);
        pool[1] = hashmix(0u);
        pool[2] = hashmix(0u);
        pool[3] = hashmix(0u);
        for (int s = 0; s < 4; ++s)
            for (int d = 0; d < 4; ++d)
                if (s != d) pool[d] = mixfn(pool[d], hashmix(pool[s]));
        uint32_t st[8];
        uint32_t hb = 0x8b51f9ddu;  // INIT_B
        for (int i = 0; i < 8; ++i) {
            uint32_t dv = pool[i & 3];
            dv ^= hb;
            hb *= 0x58f38dedu;  // MULT_B
            dv *= hb;
            dv ^= dv >> 16;
            st[i] = dv;
        }
        uint64_t v0 = (uint64_t)st[0] | ((uint64_t)st[1] << 32);
        uint64_t v1 = (uint64_t)st[2] | ((uint64_t)st[3] << 32);
        uint64_t v2 = (uint64_t)st[4] | ((uint64_t)st[5] << 32);
        uint64_t v3 = (uint64_t)st[6] | ((uint64_t)st[7] << 32);
        __uint128_t initstate = (((__uint128_t)v0) << 64) | v1;  // seed[0] = HIGH
        __uint128_t initseq   = (((__uint128_t)v2) << 64) | v3;
        const __uint128_t MULT = (((__uint128_t)2549297995355413924ULL) << 64) | 4865540595714422341ULL;
        state = 0;
        inc = (initseq << 1) | 1;
        state = state * MULT + inc;
        state += initstate;
        state = state * MULT + inc;
        ubuf = 0; has = 0;
    }
    __device__ uint64_t next64() {
        const __uint128_t MULT = (((__uint128_t)2549297995355413924ULL) << 64) | 4865540595714422341ULL;
        state = state * MULT + inc;  // step THEN output (XSL-RR)
        uint64_t hi = (uint64_t)(state >> 64);
        uint64_t lo = (uint64_t)state;
        uint32_t rot = (uint32_t)(state >> 122);
        uint64_t x = hi ^ lo;
        return (x >> rot) | (x << ((64u - rot) & 63u));
    }
    __device__ uint32_t next32() {
        if (has) { has = 0; return ubuf; }
        uint64_t n = next64();
        has = 1; ubuf = (uint32_t)(n >> 32);  // lo word first
        return (uint32_t)n;
    }
    __device__ double nextd() {
        return (double)(next64() >> 11) * (1.0 / 9007199254740992.0);
    }
};

// perm_out[0..15] = permutation; perm_out[16] = canary fail code (0 = all ok)
__global__ void perm_kernel(const int* __restrict__ seed_ptr, int* __restrict__ perm_out) {
    if (threadIdx.x != 0 || blockIdx.x != 0) return;
    int fail = 0;
    {   // canary: np.random.default_rng(0).random(2)
        PCG128 p; p.init(0u);
        double a = p.nextd(), b = p.nextd();
        if (!(fabs(a - 0.6369616873214543) < 1e-9 && fabs(b - 0.2697867137638703) < 1e-7))
            fail |= 1;
    }
    {   // canary: np.random.default_rng(42).random(2)
        PCG128 p; p.init(42u);
        double a = p.nextd(), b = p.nextd();
        if (!(fabs(a - 0.7739560485559633) < 1e-9 && fabs(b - 0.4388784397520523) < 1e-7))
            fail |= 2;
    }
    {   // canary: threefry2x32-20 KAT key=0 ctr=0 (Random123): 6b200159 99ba4efe
        uint32_t a, b;
        threefry2x32(0u, 0u, 0u, 0u, a, b);
        bool ok = (a == 0x6b200159u && b == 0x99ba4efeu) ||
                  (a == 0x99ba4efeu && b == 0x6b200159u);
        if (!ok) fail |= 4;
    }
    perm_out[16] = fail;

    PCG128 p;
    p.init((uint32_t)(*seed_ptr));
    int perm[16];
    for (int i = 0; i < 16; ++i) perm[i] = i;
    for (int i = 15; i >= 1; --i) {
        uint32_t mask = (uint32_t)i;
        mask |= mask >> 1; mask |= mask >> 2; mask |= mask >> 4;
        mask |= mask >> 8; mask |= mask >> 16;
        uint32_t j;
        do { j = p.next32() & mask; } while (j > (uint32_t)i);
        int tmp = perm[i]; perm[i] = perm[j]; perm[j] = tmp;
    }
    for (int i = 0; i < 16; ++i) perm_out[i] = perm[i];
}

// ---------------- fused 6-layer flow kernel ----------------
__global__ __launch_bounds__(NTHREADS, 2) void flow_kernel(
    const float* __restrict__ arm0, const float* __restrict__ cx,
    const float* __restrict__ cy, const float* __restrict__ cc,
    const float* __restrict__ W1, const float* __restrict__ b1,
    const float* __restrict__ W2, const float* __restrict__ b2,
    const float* __restrict__ W3, const float* __restrict__ b3,
    const int* __restrict__ perm, float* __restrict__ out)
{
    __shared__ float h1[ROWS][H_SZ];
    __shared__ float cib[ROWS][IN_DIM + 1];
    __shared__ float xln[ROWS][IN_DIM + 1];
    __shared__ float armb[ROWS][D_SZ];
    __shared__ float outb[ROWS][D_SZ];
    __shared__ float carb[ROWS][3];
    __shared__ float ldjb[ROWS];
    __shared__ int   permS[D_SZ];

    const int t = threadIdx.x;
    const int row0 = blockIdx.x * ROWS;

    if (t < ROWS * D_SZ) armb[t / D_SZ][t % D_SZ] = arm0[row0 * D_SZ + t];
    if (t < ROWS) {
        carb[t][0] = cx[row0 + t];
        carb[t][1] = cy[row0 + t];
        carb[t][2] = cc[row0 + t];
        ldjb[t] = 0.0f;
    }
    if (t < D_SZ) permS[t] = perm[t];
    __syncthreads();

    for (int layer = 0; layer < NLAYERS; ++layer) {
        if (t < ROWS * IN_DIM) {
            int r = t / IN_DIM, j = t % IN_DIM;
            float base = (j < HALF_SZ) ? armb[r][j] : carb[r][j - HALF_SZ];
            uint32_t m = (uint32_t)(layer * (B_SZ * IN_DIM) + (row0 + r) * IN_DIM + j);
            cib[r][j] = base + noise_at(m);
        }
        __syncthreads();
        if (t < ROWS) {
            float s = 0.0f;
            for (int j = 0; j < IN_DIM; ++j) s += cib[t][j];
            float mu = s / 11.0f;
            float v = 0.0f;
            for (int j = 0; j < IN_DIM; ++j) {
                float d = cib[t][j] - mu;
                v += d * d;
            }
            float inv = 1.0f / sqrtf(v / 10.0f);
            for (int j = 0; j < IN_DIM; ++j) xln[t][j] = (cib[t][j] - mu) * inv;
        }
        __syncthreads();
        // h1 = relu(x @ W1 + b1)
        for (int cq = 0; cq < H_SZ / NTHREADS; ++cq) {
            int j = t + cq * NTHREADS;
            float acc[ROWS];
            float bb = b1[j];
            #pragma unroll
            for (int r = 0; r < ROWS; ++r) acc[r] = bb;
            for (int k = 0; k < IN_DIM; ++k) {
                float w = W1[k * H_SZ + j];
                #pragma unroll
                for (int r = 0; r < ROWS; ++r) acc[r] = fmaf(xln[r][k], w, acc[r]);
            }
            #pragma unroll
            for (int r = 0; r < ROWS; ++r) h1[r][j] = fmaxf(acc[r], 0.0f);
        }
        __syncthreads();
        // h2 = relu(h1 @ W2 + b2), 8x8 register tile
        {
            const int j0 = t * 8;
            float acc[ROWS][8];
            #pragma unroll
            for (int c = 0; c < 8; ++c) {
                float bb = b2[j0 + c];
                #pragma unroll
                for (int r = 0; r < ROWS; ++r) acc[r][c] = bb;
            }
            for (int k = 0; k < H_SZ; k += 4) {
                float av[ROWS][4];
                #pragma unroll
                for (int r = 0; r < ROWS; ++r) {
                    float4 hv = *reinterpret_cast<const float4*>(&h1[r][k]);
                    av[r][0] = hv.x; av[r][1] = hv.y; av[r][2] = hv.z; av[r][3] = hv.w;
                }
                #pragma unroll
                for (int kk = 0; kk < 4; ++kk) {
                    float4 wA = *reinterpret_cast<const float4*>(&W2[(size_t)(k + kk) * H_SZ + j0]);
                    float4 wB = *reinterpret_cast<const float4*>(&W2[(size_t)(k + kk) * H_SZ + j0 + 4]);
                    float wv[8] = {wA.x, wA.y, wA.z, wA.w, wB.x, wB.y, wB.z, wB.w};
                    #pragma unroll
                    for (int r = 0; r < ROWS; ++r) {
                        #pragma unroll
                        for (int c = 0; c < 8; ++c)
                            acc[r][c] = fmaf(av[r][kk], wv[c], acc[r][c]);
                    }
                }
            }
            __syncthreads();
            #pragma unroll
            for (int r = 0; r < ROWS; ++r) {
                #pragma unroll
                for (int c = 0; c < 8; ++c)
                    h1[r][j0 + c] = fmaxf(acc[r][c], 0.0f);
            }
        }
        __syncthreads();
        // out = h2 @ W3 + b3
        if (t < ROWS * D_SZ) {
            int r = t / D_SZ, dd = t % D_SZ;
            float acc = b3[dd];
            for (int k = 0; k < H_SZ; ++k)
                acc = fmaf(h1[r][k], W3[k * D_SZ + dd], acc);
            outb[r][dd] = acc;
        }
        __syncthreads();
        // epilogue
        if (t < ROWS) {
            int r = t;
            float alt[HALF_SZ];
            float lsum = 0.0f;
            #pragma unroll
            for (int dd = 0; dd < HALF_SZ; ++dd) {
                float s  = fminf(fmaxf(outb[r][dd], -10.0f), 10.0f);
                float tt = fminf(fmaxf(outb[r][dd + HALF_SZ], -10.0f), 10.0f);
                alt[dd] = armb[r][dd + HALF_SZ] * expf(s) + tt;
                lsum += logf(fabsf(s));
            }
            ldjb[r] += lsum * (1.0f / 8.0f);
            float nc[D_SZ];
            #pragma unroll
            for (int q = 0; q < D_SZ; ++q) {
                int p = permS[q];
                nc[q] = (p < HALF_SZ) ? armb[r][p] : alt[p - HALF_SZ];
            }
            #pragma unroll
            for (int q = 0; q < D_SZ; ++q) armb[r][q] = nc[q];
        }
        __syncthreads();
    }
    if (t < ROWS * D_SZ) out[row0 * D_SZ + t] = armb[t / D_SZ][t % D_SZ];
    if (t < ROWS) out[B_SZ * D_SZ + row0 + t] = ldjb[t];

    // blind-debug sentinel: canary failures show up as absmax ~ 1.00Xe+09
    if (blockIdx.x == 0 && t == 0) {
        int fc = perm[16];
        if (fc != 0) out[0] = 1.0e9f * (1.0f + 0.001f * (float)fc);
    }
}

extern "C" void kernel_launch(void* const* d_in, const int* in_sizes, int n_in,
                              void* d_out, int out_size, void* d_ws, size_t ws_size,
                              hipStream_t stream) {
    const float* arm = (const float*)d_in[0];
    const float* cx  = (const float*)d_in[1];
    const float* cy  = (const float*)d_in[2];
    const float* cc  = (const float*)d_in[3];
    const float* W1  = (const float*)d_in[4];
    const float* b1  = (const float*)d_in[5];
    const float* W2  = (const float*)d_in[6];
    const float* b2  = (const float*)d_in[7];
    const float* W3  = (const float*)d_in[8];
    const float* b3  = (const float*)d_in[9];
    const int* seed  = (const int*)d_in[10];
    float* out = (float*)d_out;
    int* perm = (int*)d_ws;

    hipLaunchKernelGGL(perm_kernel, dim3(1), dim3(64), 0, stream, seed, perm);
    hipLaunchKernelGGL(flow_kernel, dim3(B_SZ / ROWS), dim3(NTHREADS), 0, stream,
                       arm, cx, cy, cc, W1, b1, W2, b2, W3, b3, perm, out);
}

// Round 11
// 7170.482 us; speedup vs baseline: 3.5423x; 3.5423x over previous
//
#include <hip/hip_runtime.h>
#include <stdint.h>

#define B_SZ 32768
#define D_SZ 16
#define HALF_SZ 8
#define IN_DIM 11
#define H_SZ 2048
#define NLAYERS 6

typedef unsigned short u16;
typedef __attribute__((ext_vector_type(8))) short bf16x8;
typedef __attribute__((ext_vector_type(4))) float f32x4;

// ---------------- threefry2x32-20 ----------------
__device__ __forceinline__ uint32_t rotl32(uint32_t v, int n) {
    return (v << n) | (v >> (32 - n));
}

__device__ __forceinline__ void threefry2x32(uint32_t k0, uint32_t k1,
                                             uint32_t c0, uint32_t c1,
                                             uint32_t& o0, uint32_t& o1) {
    const uint32_t k2 = k0 ^ k1 ^ 0x1BD11BDAu;
    uint32_t x0 = c0 + k0, x1 = c1 + k1;
    x0 += x1; x1 = rotl32(x1, 13); x1 ^= x0;
    x0 += x1; x1 = rotl32(x1, 15); x1 ^= x0;
    x0 += x1; x1 = rotl32(x1, 26); x1 ^= x0;
    x0 += x1; x1 = rotl32(x1,  6); x1 ^= x0;
    x0 += k1; x1 += k2 + 1u;
    x0 += x1; x1 = rotl32(x1, 17); x1 ^= x0;
    x0 += x1; x1 = rotl32(x1, 29); x1 ^= x0;
    x0 += x1; x1 = rotl32(x1, 16); x1 ^= x0;
    x0 += x1; x1 = rotl32(x1, 24); x1 ^= x0;
    x0 += k2; x1 += k0 + 2u;
    x0 += x1; x1 = rotl32(x1, 13); x1 ^= x0;
    x0 += x1; x1 = rotl32(x1, 15); x1 ^= x0;
    x0 += x1; x1 = rotl32(x1, 26); x1 ^= x0;
    x0 += x1; x1 = rotl32(x1,  6); x1 ^= x0;
    x0 += k0; x1 += k1 + 3u;
    x0 += x1; x1 = rotl32(x1, 17); x1 ^= x0;
    x0 += x1; x1 = rotl32(x1, 29); x1 ^= x0;
    x0 += x1; x1 = rotl32(x1, 16); x1 ^= x0;
    x0 += x1; x1 = rotl32(x1, 24); x1 ^= x0;
    x0 += k1; x1 += k2 + 4u;
    x0 += x1; x1 = rotl32(x1, 13); x1 ^= x0;
    x0 += x1; x1 = rotl32(x1, 15); x1 ^= x0;
    x0 += x1; x1 = rotl32(x1, 26); x1 ^= x0;
    x0 += x1; x1 = rotl32(x1,  6); x1 ^= x0;
    x0 += k2; x1 += k0 + 5u;
    o0 = x0; o1 = x1;
}

// verified rounds 4-7: partitionable layout, xor-fold of the two output words
__device__ float noise_at(uint32_t m) {
    uint32_t o0, o1;
    threefry2x32(0u, 42u, 0u, m, o0, o1);
    uint32_t bits = o0 ^ o1;
    float f = __uint_as_float((bits >> 9) | 0x3f800000u) - 1.0f;
    float u = fmaf(f, 2.0f, -0.99999994f);
    u = fmaxf(-0.99999994f, u);
    float w = -log1pf(-u * u);
    float p;
    if (w < 5.0f) {
        w = w - 2.5f;
        p = 2.81022636e-08f;
        p = fmaf(p, w, 3.43273939e-07f);
        p = fmaf(p, w, -3.5233877e-06f);
        p = fmaf(p, w, -4.39150654e-06f);
        p = fmaf(p, w, 0.00021858087f);
        p = fmaf(p, w, -0.00125372503f);
        p = fmaf(p, w, -0.00417768164f);
        p = fmaf(p, w, 0.246640727f);
        p = fmaf(p, w, 1.50140941f);
    } else {
        w = sqrtf(w) - 3.0f;
        p = -0.000200214257f;
        p = fmaf(p, w, 0.000100950558f);
        p = fmaf(p, w, 0.00134934322f);
        p = fmaf(p, w, -0.00367342844f);
        p = fmaf(p, w, 0.00573950773f);
        p = fmaf(p, w, -0.0076224613f);
        p = fmaf(p, w, 0.00943887047f);
        p = fmaf(p, w, 1.00167406f);
        p = fmaf(p, w, 2.83297682f);
    }
    float nrm = 1.4142135623730951f * (p * u);
    return nrm * 0.05f;
}

// ---------------- numpy SeedSequence -> PCG64 (canary-verified round 7) ----------------
struct PCG128 {
    __uint128_t state, inc;
    uint32_t ubuf; int has;
    __device__ void init(uint32_t entropy) {
        uint32_t pool[4];
        uint32_t hc = 0x43b0d7e5u;
        auto hashmix = [&hc](uint32_t val) {
            val ^= hc; hc *= 0x931e8875u; val *= hc; val ^= val >> 16; return val;
        };
        auto mixfn = [](uint32_t x, uint32_t y) {
            uint32_t r = x * 0xca01f9ddu - y * 0x4973f715u; r ^= r >> 16; return r;
        };
        pool[0] = hashmix(entropy);
        pool[1] = hashmix(0u); pool[2] = hashmix(0u); pool[3] = hashmix(0u);
        for (int s = 0; s < 4; ++s)
            for (int d = 0; d < 4; ++d)
                if (s != d) pool[d] = mixfn(pool[d], hashmix(pool[s]));
        uint32_t st[8];
        uint32_t hb = 0x8b51f9ddu;
        for (int i = 0; i < 8; ++i) {
            uint32_t dv = pool[i & 3];
            dv ^= hb; hb *= 0x58f38dedu; dv *= hb; dv ^= dv >> 16;
            st[i] = dv;
        }
        uint64_t v0 = (uint64_t)st[0] | ((uint64_t)st[1] << 32);
        uint64_t v1 = (uint64_t)st[2] | ((uint64_t)st[3] << 32);
        uint64_t v2 = (uint64_t)st[4] | ((uint64_t)st[5] << 32);
        uint64_t v3 = (uint64_t)st[6] | ((uint64_t)st[7] << 32);
        __uint128_t initstate = (((__uint128_t)v0) << 64) | v1;
        __uint128_t initseq   = (((__uint128_t)v2) << 64) | v3;
        const __uint128_t MULT = (((__uint128_t)2549297995355413924ULL) << 64) | 4865540595714422341ULL;
        state = 0;
        inc = (initseq << 1) | 1;
        state = state * MULT + inc;
        state += initstate;
        state = state * MULT + inc;
        ubuf = 0; has = 0;
    }
    __device__ uint64_t next64() {
        const __uint128_t MULT = (((__uint128_t)2549297995355413924ULL) << 64) | 4865540595714422341ULL;
        state = state * MULT + inc;
        uint64_t hi = (uint64_t)(state >> 64);
        uint64_t lo = (uint64_t)state;
        uint32_t rot = (uint32_t)(state >> 122);
        uint64_t x = hi ^ lo;
        return (x >> rot) | (x << ((64u - rot) & 63u));
    }
    __device__ uint32_t next32() {
        if (has) { has = 0; return ubuf; }
        uint64_t n = next64();
        has = 1; ubuf = (uint32_t)(n >> 32);
        return (uint32_t)n;
    }
};

__global__ void perm_kernel(const int* __restrict__ seed_ptr, int* __restrict__ perm_out) {
    if (threadIdx.x != 0 || blockIdx.x != 0) return;
    PCG128 p;
    p.init((uint32_t)(*seed_ptr));
    int perm[16];
    for (int i = 0; i < 16; ++i) perm[i] = i;
    for (int i = 15; i >= 1; --i) {
        uint32_t mask = (uint32_t)i;
        mask |= mask >> 1; mask |= mask >> 2; mask |= mask >> 4;
        mask |= mask >> 8; mask |= mask >> 16;
        uint32_t j;
        do { j = p.next32() & mask; } while (j > (uint32_t)i);
        int tmp = perm[i]; perm[i] = perm[j]; perm[j] = tmp;
    }
    for (int i = 0; i < 16; ++i) perm_out[i] = perm[i];
}

// ---------------- bf16 split helpers ----------------
__device__ __forceinline__ u16 bf16rn(float f) {
    uint32_t u = __float_as_uint(f);
    uint32_t r = (u + 0x7fffu + ((u >> 16) & 1u)) >> 16;
    return (u16)r;
}
__device__ __forceinline__ void split2(float f, u16& hi, u16& lo) {
    hi = bf16rn(f);
    float fh = __uint_as_float(((uint32_t)hi) << 16);
    lo = bf16rn(f - fh);
}

// ---------------- W2 pre-split + transpose: Wt[n][k] hi/lo ----------------
__global__ __launch_bounds__(256) void presplit_kernel(
    const float* __restrict__ W2, u16* __restrict__ Whi, u16* __restrict__ Wlo)
{
    __shared__ float tile[32][33];
    const int bx = blockIdx.x & 63, by = blockIdx.x >> 6;
    const int tx = threadIdx.x & 31, ty = threadIdx.x >> 5;
    const int k0 = by * 32, n0 = bx * 32;
    #pragma unroll
    for (int yy = 0; yy < 32; yy += 8)
        tile[ty + yy][tx] = W2[(size_t)(k0 + ty + yy) * H_SZ + n0 + tx];
    __syncthreads();
    #pragma unroll
    for (int yy = 0; yy < 32; yy += 8) {
        float f = tile[tx][ty + yy];
        u16 hi, lo; split2(f, hi, lo);
        size_t o = (size_t)(n0 + ty + yy) * H_SZ + k0 + tx;
        Whi[o] = hi; Wlo[o] = lo;
    }
}

// ---------------- layer A: noise + layernorm + W1 -> h1 hi/lo (chunk-local) ----------------
__global__ __launch_bounds__(256) void layerA_kernel(
    const float* __restrict__ armsrc, const float* __restrict__ cx,
    const float* __restrict__ cy, const float* __restrict__ cc,
    const float* __restrict__ W1, const float* __restrict__ b1,
    u16* __restrict__ h1hi, u16* __restrict__ h1lo,
    float* __restrict__ out16, int layer, int chunk_start)
{
    __shared__ float ci[4][12];
    const int t = threadIdx.x;
    const int lane = t & 63;
    const int w = t >> 6;
    const int row_l = blockIdx.x * 4 + w;       // chunk-local
    const int row   = chunk_start + row_l;      // global

    // zero the out16 accumulator rows this block owns (gemm atomically adds later)
    if (t < 64) out16[(size_t)(blockIdx.x * 4) * 16 + t] = 0.0f;

    if (lane < IN_DIM) {
        int j = lane;
        float base = (j < HALF_SZ) ? armsrc[(size_t)row * D_SZ + j]
                   : (j == 8 ? cx[row] : (j == 9 ? cy[row] : cc[row]));
        uint32_t m = (uint32_t)(layer * (B_SZ * IN_DIM) + row * IN_DIM + j);
        ci[w][j] = base + noise_at(m);
    }
    __syncthreads();

    float s = 0.0f;
    #pragma unroll
    for (int j = 0; j < IN_DIM; ++j) s += ci[w][j];
    float mu = s / 11.0f;
    float v = 0.0f;
    #pragma unroll
    for (int j = 0; j < IN_DIM; ++j) { float d = ci[w][j] - mu; v += d * d; }
    float inv = 1.0f / sqrtf(v / 10.0f);

    float acc[32];
    #pragma unroll
    for (int jj = 0; jj < 32; ++jj) acc[jj] = b1[lane + jj * 64];
    for (int k = 0; k < IN_DIM; ++k) {
        float xk = (ci[w][k] - mu) * inv;
        const float* wr = &W1[(size_t)k * H_SZ];
        #pragma unroll
        for (int jj = 0; jj < 32; ++jj)
            acc[jj] = fmaf(xk, wr[lane + jj * 64], acc[jj]);
    }
    size_t rb = (size_t)row_l * H_SZ;
    #pragma unroll
    for (int jj = 0; jj < 32; ++jj) {
        float h = fmaxf(acc[jj], 0.0f);
        u16 hi, lo; split2(h, hi, lo);
        h1hi[rb + lane + jj * 64] = hi;
        h1lo[rb + lane + jj * 64] = lo;
    }
}

// ---------------- layer B: (relu(h1@W2+b2)) @ W3 partials -> atomicAdd out16 ----------------
#define BM 128
#define BN 128
#define BK 64

__device__ __forceinline__ f32x4 mfma16(bf16x8 a, bf16x8 b, f32x4 c) {
    return __builtin_amdgcn_mfma_f32_16x16x32_bf16(a, b, c, 0, 0, 0);
}

#define GLOAD_LDS16(gsrc, ldst) \
    __builtin_amdgcn_global_load_lds( \
        (const __attribute__((address_space(1))) void*)(gsrc), \
        (__attribute__((address_space(3))) void*)(ldst), 16, 0, 0)

__global__ __launch_bounds__(256, 2) void gemm_kernel(
    const u16* __restrict__ Ahi, const u16* __restrict__ Alo,
    const u16* __restrict__ Bhi, const u16* __restrict__ Blo,
    const float* __restrict__ b2, const float* __restrict__ W3,
    float* __restrict__ out16)
{
    __shared__ u16 lds[4][BM * BK];   // 64KB staging; reused as fp32 tile in epilogue

    const int t = threadIdx.x;
    const int nwg = gridDim.x;                    // = mtiles*16, multiple of 8
    const int bid = blockIdx.x;
    const int swz = (bid & 7) * (nwg >> 3) + (bid >> 3);   // bijective XCD swizzle
    const int m0 = (swz >> 4) * BM;               // chunk-local row base
    const int n0 = (swz & 15) * BN;               // global col base

    const int lane = t & 63;
    const int w = t >> 6;
    const int wrow = (w >> 1) * 64;
    const int wcol = (w & 1) * 64;
    const int fr = lane & 15;
    const int kc = (lane >> 4) * 8;

    f32x4 acc[4][4];
    const int colbase = n0 + wcol + fr;
    #pragma unroll
    for (int nc = 0; nc < 4; ++nc) {
        float b = b2[colbase + nc * 16];
        #pragma unroll
        for (int mr = 0; mr < 4; ++mr) acc[mr][nc] = (f32x4){b, b, b, b};
    }

    const int r0 = t >> 3;
    const int c8 = (t & 7) * 8;
    for (int ks = 0; ks < H_SZ / BK; ++ks) {
        const int k0 = ks * BK;
        #pragma unroll
        for (int p = 0; p < 4; ++p) {
            const int r = r0 + p * 32;
            const size_t ga = (size_t)(m0 + r) * H_SZ + k0 + c8;
            const size_t gb = (size_t)(n0 + r) * H_SZ + k0 + c8;
            const int lofs = (t + p * 256) * 8;
            GLOAD_LDS16(Ahi + ga, &lds[0][lofs]);
            GLOAD_LDS16(Alo + ga, &lds[1][lofs]);
            GLOAD_LDS16(Bhi + gb, &lds[2][lofs]);
            GLOAD_LDS16(Blo + gb, &lds[3][lofs]);
        }
        __syncthreads();

        #pragma unroll
        for (int half = 0; half < 2; ++half) {
            const int kb = half * 32 + kc;
            bf16x8 ah[4], al[4], bh[4], bl[4];
            #pragma unroll
            for (int mr = 0; mr < 4; ++mr) {
                const int r = (wrow + mr * 16 + fr) * BK + kb;
                ah[mr] = *(const bf16x8*)&lds[0][r];
                al[mr] = *(const bf16x8*)&lds[1][r];
            }
            #pragma unroll
            for (int nc = 0; nc < 4; ++nc) {
                const int r = (wcol + nc * 16 + fr) * BK + kb;
                bh[nc] = *(const bf16x8*)&lds[2][r];
                bl[nc] = *(const bf16x8*)&lds[3][r];
            }
            #pragma unroll
            for (int mr = 0; mr < 4; ++mr) {
                #pragma unroll
                for (int nc = 0; nc < 4; ++nc) {
                    acc[mr][nc] = mfma16(al[mr], bh[nc], acc[mr][nc]);
                    acc[mr][nc] = mfma16(ah[mr], bl[nc], acc[mr][nc]);
                    acc[mr][nc] = mfma16(ah[mr], bh[nc], acc[mr][nc]);
                }
            }
        }
        __syncthreads();
    }

    // ---- epilogue: relu into LDS fp32 tile, then partial h2@W3 -> atomicAdd ----
    float* ftile = (float*)&lds[0][0];   // 128*128*4B = 64KB, exactly the staging LDS
    const int rfrag = (lane >> 4) * 4;   // D layout: col=lane&15, row=(lane>>4)*4+j
    #pragma unroll
    for (int mr = 0; mr < 4; ++mr) {
        #pragma unroll
        for (int j = 0; j < 4; ++j) {
            const int rr = wrow + mr * 16 + rfrag + j;
            #pragma unroll
            for (int nc = 0; nc < 4; ++nc)
                ftile[rr * BN + wcol + nc * 16 + fr] = fmaxf(acc[mr][nc][j], 0.0f);
        }
    }
    __syncthreads();

    // thread t: row r = t>>1 (0..127), d-range (t&1)*8..+7
    {
        const int r = t >> 1;
        const int d0 = (t & 1) * 8;
        float sum[8];
        #pragma unroll
        for (int i = 0; i < 8; ++i) sum[i] = 0.0f;
        for (int c = 0; c < BN; ++c) {
            float hv = ftile[r * BN + c];
            const float4* w3p = (const float4*)&W3[(size_t)(n0 + c) * 16 + d0];
            float4 a = w3p[0], b = w3p[1];
            sum[0] = fmaf(hv, a.x, sum[0]); sum[1] = fmaf(hv, a.y, sum[1]);
            sum[2] = fmaf(hv, a.z, sum[2]); sum[3] = fmaf(hv, a.w, sum[3]);
            sum[4] = fmaf(hv, b.x, sum[4]); sum[5] = fmaf(hv, b.y, sum[5]);
            sum[6] = fmaf(hv, b.z, sum[6]); sum[7] = fmaf(hv, b.w, sum[7]);
        }
        float* orow = &out16[(size_t)(m0 + r) * 16 + d0];
        #pragma unroll
        for (int i = 0; i < 8; ++i) atomicAdd(&orow[i], sum[i]);
    }
}

// ---------------- layer C: epilogue + permute (reads tiny out16) ----------------
__global__ __launch_bounds__(256) void layerC_kernel(
    const float* __restrict__ out16, const float* __restrict__ b3,
    const float* __restrict__ armsrc, float* __restrict__ armdst,
    float* __restrict__ ldjws, const int* __restrict__ perm,
    float* __restrict__ outfinal, int layer, int chunk_start, int rows_c)
{
    const int row_l = blockIdx.x * 256 + threadIdx.x;
    if (row_l >= rows_c) return;
    const int row = chunk_start + row_l;

    float armRow[16];
    #pragma unroll
    for (int q = 0; q < 16; ++q) armRow[q] = armsrc[(size_t)row * D_SZ + q];

    float alt[8];
    float lsum = 0.0f;
    #pragma unroll
    for (int dd = 0; dd < 8; ++dd) {
        float sv = fminf(fmaxf(out16[(size_t)row_l * 16 + dd] + b3[dd], -10.0f), 10.0f);
        float tv = fminf(fmaxf(out16[(size_t)row_l * 16 + dd + 8] + b3[dd + 8], -10.0f), 10.0f);
        alt[dd] = armRow[dd + 8] * expf(sv) + tv;
        lsum += logf(fabsf(sv));
    }
    float lprev = (layer == 0) ? 0.0f : ldjws[row];
    float lnew = lprev + lsum * 0.125f;

    float nc[16];
    #pragma unroll
    for (int q = 0; q < 16; ++q) {
        int pi = perm[q];
        nc[q] = (pi < 8) ? armRow[pi] : alt[pi - 8];
    }
    if (layer == NLAYERS - 1) {
        #pragma unroll
        for (int q = 0; q < 16; ++q) outfinal[(size_t)row * D_SZ + q] = nc[q];
        outfinal[(size_t)B_SZ * D_SZ + row] = lnew;
    } else {
        #pragma unroll
        for (int q = 0; q < 16; ++q) armdst[(size_t)row * D_SZ + q] = nc[q];
        ldjws[row] = lnew;
    }
}

extern "C" void kernel_launch(void* const* d_in, const int* in_sizes, int n_in,
                              void* d_out, int out_size, void* d_ws, size_t ws_size,
                              hipStream_t stream) {
    const float* arm = (const float*)d_in[0];
    const float* cx  = (const float*)d_in[1];
    const float* cy  = (const float*)d_in[2];
    const float* cc  = (const float*)d_in[3];
    const float* W1  = (const float*)d_in[4];
    const float* b1  = (const float*)d_in[5];
    const float* W2  = (const float*)d_in[6];
    const float* b2  = (const float*)d_in[7];
    const float* W3  = (const float*)d_in[8];
    const float* b3  = (const float*)d_in[9];
    const int* seed  = (const int*)d_in[10];
    float* out = (float*)d_out;

    char* ws = (char*)d_ws;
    size_t cur = 0;
    auto alloc = [&](size_t bytes) {
        size_t off = cur;
        cur += (bytes + 255) & ~(size_t)255;
        return (void*)(ws + off);
    };
    // fixed allocations (~19 MB)
    int*   perm   = (int*)  alloc(64);
    float* arm_ws = (float*)alloc((size_t)B_SZ * D_SZ * 4);
    float* ldj_ws = (float*)alloc((size_t)B_SZ * 4);
    u16*   W2thi  = (u16*)  alloc((size_t)H_SZ * H_SZ * 2);
    u16*   W2tlo  = (u16*)  alloc((size_t)H_SZ * H_SZ * 2);

    // adaptive chunk: per-row cost = h1hi+h1lo (2048*2*2B) + out16 (64B) = 8256 B
    long chunk = B_SZ;
    {
        size_t fixed = cur + 4096;  // slack for alignment pads
        size_t avail = (ws_size > fixed) ? (ws_size - fixed) : 0;
        long c = (long)(avail / 8256);
        c = (c / 128) * 128;
        if (c < 128) c = 128;       // nothing smaller is possible; 128 needs ~20 MB total
        if (c > B_SZ) c = B_SZ;
        chunk = c;
    }
    u16*   h1hi  = (u16*)  alloc((size_t)chunk * H_SZ * 2);
    u16*   h1lo  = (u16*)  alloc((size_t)chunk * H_SZ * 2);
    float* out16 = (float*)alloc((size_t)chunk * 16 * 4);

    hipLaunchKernelGGL(perm_kernel, dim3(1), dim3(64), 0, stream, seed, perm);
    hipLaunchKernelGGL(presplit_kernel, dim3(4096), dim3(256), 0, stream, W2, W2thi, W2tlo);

    for (long cs = 0; cs < B_SZ; cs += chunk) {
        long rc = B_SZ - cs;
        if (rc > chunk) rc = chunk;          // always a multiple of 128
        for (int layer = 0; layer < NLAYERS; ++layer) {
            const float* asrc = (layer == 0) ? arm : arm_ws;
            hipLaunchKernelGGL(layerA_kernel, dim3(rc / 4), dim3(256), 0, stream,
                               asrc, cx, cy, cc, W1, b1, h1hi, h1lo, out16,
                               layer, (int)cs);
            hipLaunchKernelGGL(gemm_kernel, dim3((rc / BM) * (H_SZ / BN)), dim3(256), 0, stream,
                               h1hi, h1lo, W2thi, W2tlo, b2, W3, out16);
            hipLaunchKernelGGL(layerC_kernel, dim3((rc + 255) / 256), dim3(256), 0, stream,
                               out16, b3, asrc, arm_ws, ldj_ws, perm, out,
                               layer, (int)cs, (int)rc);
        }
    }
}

// Round 13
// 6670.895 us; speedup vs baseline: 3.8076x; 1.0749x over previous
//
#include <hip/hip_runtime.h>
#include <stdint.h>

#define B_SZ 32768
#define D_SZ 16
#define HALF_SZ 8
#define IN_DIM 11
#define H_SZ 2048
#define NLAYERS 6

typedef unsigned short u16;
typedef __attribute__((ext_vector_type(8))) short bf16x8;
typedef __attribute__((ext_vector_type(4))) float f32x4;

// ---------------- threefry2x32-20 ----------------
__device__ __forceinline__ uint32_t rotl32(uint32_t v, int n) {
    return (v << n) | (v >> (32 - n));
}

__device__ __forceinline__ void threefry2x32(uint32_t k0, uint32_t k1,
                                             uint32_t c0, uint32_t c1,
                                             uint32_t& o0, uint32_t& o1) {
    const uint32_t k2 = k0 ^ k1 ^ 0x1BD11BDAu;
    uint32_t x0 = c0 + k0, x1 = c1 + k1;
    x0 += x1; x1 = rotl32(x1, 13); x1 ^= x0;
    x0 += x1; x1 = rotl32(x1, 15); x1 ^= x0;
    x0 += x1; x1 = rotl32(x1, 26); x1 ^= x0;
    x0 += x1; x1 = rotl32(x1,  6); x1 ^= x0;
    x0 += k1; x1 += k2 + 1u;
    x0 += x1; x1 = rotl32(x1, 17); x1 ^= x0;
    x0 += x1; x1 = rotl32(x1, 29); x1 ^= x0;
    x0 += x1; x1 = rotl32(x1, 16); x1 ^= x0;
    x0 += x1; x1 = rotl32(x1, 24); x1 ^= x0;
    x0 += k2; x1 += k0 + 2u;
    x0 += x1; x1 = rotl32(x1, 13); x1 ^= x0;
    x0 += x1; x1 = rotl32(x1, 15); x1 ^= x0;
    x0 += x1; x1 = rotl32(x1, 26); x1 ^= x0;
    x0 += x1; x1 = rotl32(x1,  6); x1 ^= x0;
    x0 += k0; x1 += k1 + 3u;
    x0 += x1; x1 = rotl32(x1, 17); x1 ^= x0;
    x0 += x1; x1 = rotl32(x1, 29); x1 ^= x0;
    x0 += x1; x1 = rotl32(x1, 16); x1 ^= x0;
    x0 += x1; x1 = rotl32(x1, 24); x1 ^= x0;
    x0 += k1; x1 += k2 + 4u;
    x0 += x1; x1 = rotl32(x1, 13); x1 ^= x0;
    x0 += x1; x1 = rotl32(x1, 15); x1 ^= x0;
    x0 += x1; x1 = rotl32(x1, 26); x1 ^= x0;
    x0 += x1; x1 = rotl32(x1,  6); x1 ^= x0;
    x0 += k2; x1 += k0 + 5u;
    o0 = x0; o1 = x1;
}

// verified rounds 4-11: partitionable layout, xor-fold of the two output words
__device__ float noise_at(uint32_t m) {
    uint32_t o0, o1;
    threefry2x32(0u, 42u, 0u, m, o0, o1);
    uint32_t bits = o0 ^ o1;
    float f = __uint_as_float((bits >> 9) | 0x3f800000u) - 1.0f;
    float u = fmaf(f, 2.0f, -0.99999994f);
    u = fmaxf(-0.99999994f, u);
    float w = -log1pf(-u * u);
    float p;
    if (w < 5.0f) {
        w = w - 2.5f;
        p = 2.81022636e-08f;
        p = fmaf(p, w, 3.43273939e-07f);
        p = fmaf(p, w, -3.5233877e-06f);
        p = fmaf(p, w, -4.39150654e-06f);
        p = fmaf(p, w, 0.00021858087f);
        p = fmaf(p, w, -0.00125372503f);
        p = fmaf(p, w, -0.00417768164f);
        p = fmaf(p, w, 0.246640727f);
        p = fmaf(p, w, 1.50140941f);
    } else {
        w = sqrtf(w) - 3.0f;
        p = -0.000200214257f;
        p = fmaf(p, w, 0.000100950558f);
        p = fmaf(p, w, 0.00134934322f);
        p = fmaf(p, w, -0.00367342844f);
        p = fmaf(p, w, 0.00573950773f);
        p = fmaf(p, w, -0.0076224613f);
        p = fmaf(p, w, 0.00943887047f);
        p = fmaf(p, w, 1.00167406f);
        p = fmaf(p, w, 2.83297682f);
    }
    float nrm = 1.4142135623730951f * (p * u);
    return nrm * 0.05f;
}

// ---------------- numpy SeedSequence -> PCG64 (canary-verified round 7) ----------------
struct PCG128 {
    __uint128_t state, inc;
    uint32_t ubuf; int has;
    __device__ void init(uint32_t entropy) {
        uint32_t pool[4];
        uint32_t hc = 0x43b0d7e5u;
        auto hashmix = [&hc](uint32_t val) {
            val ^= hc; hc *= 0x931e8875u; val *= hc; val ^= val >> 16; return val;
        };
        auto mixfn = [](uint32_t x, uint32_t y) {
            uint32_t r = x * 0xca01f9ddu - y * 0x4973f715u; r ^= r >> 16; return r;
        };
        pool[0] = hashmix(entropy);
        pool[1] = hashmix(0u); pool[2] = hashmix(0u); pool[3] = hashmix(0u);
        for (int s = 0; s < 4; ++s)
            for (int d = 0; d < 4; ++d)
                if (s != d) pool[d] = mixfn(pool[d], hashmix(pool[s]));
        uint32_t st[8];
        uint32_t hb = 0x8b51f9ddu;
        for (int i = 0; i < 8; ++i) {
            uint32_t dv = pool[i & 3];
            dv ^= hb; hb *= 0x58f38dedu; dv *= hb; dv ^= dv >> 16;
            st[i] = dv;
        }
        uint64_t v0 = (uint64_t)st[0] | ((uint64_t)st[1] << 32);
        uint64_t v1 = (uint64_t)st[2] | ((uint64_t)st[3] << 32);
        uint64_t v2 = (uint64_t)st[4] | ((uint64_t)st[5] << 32);
        uint64_t v3 = (uint64_t)st[6] | ((uint64_t)st[7] << 32);
        __uint128_t initstate = (((__uint128_t)v0) << 64) | v1;
        __uint128_t initseq   = (((__uint128_t)v2) << 64) | v3;
        const __uint128_t MULT = (((__uint128_t)2549297995355413924ULL) << 64) | 4865540595714422341ULL;
        state = 0;
        inc = (initseq << 1) | 1;
        state = state * MULT + inc;
        state += initstate;
        state = state * MULT + inc;
        ubuf = 0; has = 0;
    }
    __device__ uint64_t next64() {
        const __uint128_t MULT = (((__uint128_t)2549297995355413924ULL) << 64) | 4865540595714422341ULL;
        state = state * MULT + inc;
        uint64_t hi = (uint64_t)(state >> 64);
        uint64_t lo = (uint64_t)state;
        uint32_t rot = (uint32_t)(state >> 122);
        uint64_t x = hi ^ lo;
        return (x >> rot) | (x << ((64u - rot) & 63u));
    }
    __device__ uint32_t next32() {
        if (has) { has = 0; return ubuf; }
        uint64_t n = next64();
        has = 1; ubuf = (uint32_t)(n >> 32);
        return (uint32_t)n;
    }
};

__global__ void perm_kernel(const int* __restrict__ seed_ptr, int* __restrict__ perm_out) {
    if (threadIdx.x != 0 || blockIdx.x != 0) return;
    PCG128 p;
    p.init((uint32_t)(*seed_ptr));
    int perm[16];
    for (int i = 0; i < 16; ++i) perm[i] = i;
    for (int i = 15; i >= 1; --i) {
        uint32_t mask = (uint32_t)i;
        mask |= mask >> 1; mask |= mask >> 2; mask |= mask >> 4;
        mask |= mask >> 8; mask |= mask >> 16;
        uint32_t j;
        do { j = p.next32() & mask; } while (j > (uint32_t)i);
        int tmp = perm[i]; perm[i] = perm[j]; perm[j] = tmp;
    }
    for (int i = 0; i < 16; ++i) perm_out[i] = perm[i];
}

// ---------------- bf16 split helpers ----------------
__device__ __forceinline__ u16 bf16rn(float f) {
    uint32_t u = __float_as_uint(f);
    uint32_t r = (u + 0x7fffu + ((u >> 16) & 1u)) >> 16;
    return (u16)r;
}
__device__ __forceinline__ void split2(float f, u16& hi, u16& lo) {
    hi = bf16rn(f);
    float fh = __uint_as_float(((uint32_t)hi) << 16);
    lo = bf16rn(f - fh);
}

// ---------------- W2 pre-split + transpose: Wt[n][k] hi/lo ----------------
__global__ __launch_bounds__(256) void presplit_kernel(
    const float* __restrict__ W2, u16* __restrict__ Whi, u16* __restrict__ Wlo)
{
    __shared__ float tile[32][33];
    const int bx = blockIdx.x & 63, by = blockIdx.x >> 6;
    const int tx = threadIdx.x & 31, ty = threadIdx.x >> 5;
    const int k0 = by * 32, n0 = bx * 32;
    #pragma unroll
    for (int yy = 0; yy < 32; yy += 8)
        tile[ty + yy][tx] = W2[(size_t)(k0 + ty + yy) * H_SZ + n0 + tx];
    __syncthreads();
    #pragma unroll
    for (int yy = 0; yy < 32; yy += 8) {
        float f = tile[tx][ty + yy];
        u16 hi, lo; split2(f, hi, lo);
        size_t o = (size_t)(n0 + ty + yy) * H_SZ + k0 + tx;
        Whi[o] = hi; Wlo[o] = lo;
    }
}

// ---------------- layer A: noise + layernorm + W1 -> h1 hi/lo (chunk-local) ----------------
__global__ __launch_bounds__(256) void layerA_kernel(
    const float* __restrict__ armsrc, const float* __restrict__ cx,
    const float* __restrict__ cy, const float* __restrict__ cc,
    const float* __restrict__ W1, const float* __restrict__ b1,
    u16* __restrict__ h1hi, u16* __restrict__ h1lo,
    float* __restrict__ out16, int layer, int chunk_start)
{
    __shared__ float ci[4][12];
    const int t = threadIdx.x;
    const int lane = t & 63;
    const int w = t >> 6;
    const int row_l = blockIdx.x * 4 + w;       // chunk-local
    const int row   = chunk_start + row_l;      // global

    // zero the out16 accumulator rows this block owns (gemm atomically adds later)
    if (t < 64) out16[(size_t)(blockIdx.x * 4) * 16 + t] = 0.0f;

    if (lane < IN_DIM) {
        int j = lane;
        float base = (j < HALF_SZ) ? armsrc[(size_t)row * D_SZ + j]
                   : (j == 8 ? cx[row] : (j == 9 ? cy[row] : cc[row]));
        uint32_t m = (uint32_t)(layer * (B_SZ * IN_DIM) + row * IN_DIM + j);
        ci[w][j] = base + noise_at(m);
    }
    __syncthreads();

    float s = 0.0f;
    #pragma unroll
    for (int j = 0; j < IN_DIM; ++j) s += ci[w][j];
    float mu = s / 11.0f;
    float v = 0.0f;
    #pragma unroll
    for (int j = 0; j < IN_DIM; ++j) { float d = ci[w][j] - mu; v += d * d; }
    float inv = 1.0f / sqrtf(v / 10.0f);

    float acc[32];
    #pragma unroll
    for (int jj = 0; jj < 32; ++jj) acc[jj] = b1[lane + jj * 64];
    for (int k = 0; k < IN_DIM; ++k) {
        float xk = (ci[w][k] - mu) * inv;
        const float* wr = &W1[(size_t)k * H_SZ];
        #pragma unroll
        for (int jj = 0; jj < 32; ++jj)
            acc[jj] = fmaf(xk, wr[lane + jj * 64], acc[jj]);
    }
    size_t rb = (size_t)row_l * H_SZ;
    #pragma unroll
    for (int jj = 0; jj < 32; ++jj) {
        float h = fmaxf(acc[jj], 0.0f);
        u16 hi, lo; split2(h, hi, lo);
        h1hi[rb + lane + jj * 64] = hi;
        h1lo[rb + lane + jj * 64] = lo;
    }
}

// ---------------- layer B: (relu(h1@W2+b2)) @ W3 partials -> atomicAdd out16 ----------------
#define BM 128
#define BN 128
#define BK 64

__device__ __forceinline__ f32x4 mfma16(bf16x8 a, bf16x8 b, f32x4 c) {
    return __builtin_amdgcn_mfma_f32_16x16x32_bf16(a, b, c, 0, 0, 0);
}

#define GLOAD_LDS16(gsrc, ldst) \
    __builtin_amdgcn_global_load_lds( \
        (const __attribute__((address_space(1))) void*)(gsrc), \
        (__attribute__((address_space(3))) void*)(ldst), 16, 0, 0)

__global__ __launch_bounds__(256, 2) void gemm_kernel(
    const u16* __restrict__ Ahi, const u16* __restrict__ Alo,
    const u16* __restrict__ Bhi, const u16* __restrict__ Blo,
    const float* __restrict__ b2, const float* __restrict__ W3,
    float* __restrict__ out16)
{
    __shared__ u16 lds[4][BM * BK];   // 64KB staging; reused as fp32 tile in epilogue

    const int t = threadIdx.x;
    const int nwg = gridDim.x;                    // = mtiles*16, multiple of 8
    const int bid = blockIdx.x;
    const int swz = (bid & 7) * (nwg >> 3) + (bid >> 3);   // bijective XCD swizzle
    const int m0 = (swz >> 4) * BM;               // chunk-local row base
    const int n0 = (swz & 15) * BN;               // global col base

    const int lane = t & 63;
    const int w = t >> 6;
    const int wrow = (w >> 1) * 64;
    const int wcol = (w & 1) * 64;
    const int fr = lane & 15;
    const int kc = (lane >> 4) * 8;

    f32x4 acc[4][4];
    const int colbase = n0 + wcol + fr;
    #pragma unroll
    for (int nc = 0; nc < 4; ++nc) {
        float b = b2[colbase + nc * 16];
        #pragma unroll
        for (int mr = 0; mr < 4; ++mr) acc[mr][nc] = (f32x4){b, b, b, b};
    }

    // T2 XOR-swizzle (rule #21: linear LDS dest + inverse-swizzled global
    // source + swizzled read). Swizzle in u16 units: col ^= (row&7)<<3.
    const int r0 = t >> 3;
    const int c8 = (t & 7) * 8;
    const int csw = c8 ^ ((r0 & 7) << 3);         // staging source col (r&7 == r0&7 for all p)
    const int fsw = (fr & 7) << 3;                // fragment read swizzle (row&7 == fr&7)
    for (int ks = 0; ks < H_SZ / BK; ++ks) {
        const int k0 = ks * BK;
        #pragma unroll
        for (int p = 0; p < 4; ++p) {
            const int r = r0 + p * 32;
            const size_t ga = (size_t)(m0 + r) * H_SZ + k0 + csw;
            const size_t gb = (size_t)(n0 + r) * H_SZ + k0 + csw;
            const int lofs = (t + p * 256) * 8;   // linear dest (u16 units)
            GLOAD_LDS16(Ahi + ga, &lds[0][lofs]);
            GLOAD_LDS16(Alo + ga, &lds[1][lofs]);
            GLOAD_LDS16(Bhi + gb, &lds[2][lofs]);
            GLOAD_LDS16(Blo + gb, &lds[3][lofs]);
        }
        __syncthreads();

        #pragma unroll
        for (int half = 0; half < 2; ++half) {
            const int kbs = (half * 32 + kc) ^ fsw;   // swizzled read col
            bf16x8 ah[4], al[4], bh[4], bl[4];
            #pragma unroll
            for (int mr = 0; mr < 4; ++mr) {
                const int r = (wrow + mr * 16 + fr) * BK + kbs;
                ah[mr] = *(const bf16x8*)&lds[0][r];
                al[mr] = *(const bf16x8*)&lds[1][r];
            }
            #pragma unroll
            for (int nc = 0; nc < 4; ++nc) {
                const int r = (wcol + nc * 16 + fr) * BK + kbs;
                bh[nc] = *(const bf16x8*)&lds[2][r];
                bl[nc] = *(const bf16x8*)&lds[3][r];
            }
            #pragma unroll
            for (int mr = 0; mr < 4; ++mr) {
                #pragma unroll
                for (int nc = 0; nc < 4; ++nc) {
                    acc[mr][nc] = mfma16(al[mr], bh[nc], acc[mr][nc]);
                    acc[mr][nc] = mfma16(ah[mr], bl[nc], acc[mr][nc]);
                    acc[mr][nc] = mfma16(ah[mr], bh[nc], acc[mr][nc]);
                }
            }
        }
        __syncthreads();
    }

    // ---- epilogue: relu into LDS fp32 tile, then partial h2@W3 -> atomicAdd ----
    float* ftile = (float*)&lds[0][0];   // 128*128*4B = 64KB, exactly the staging LDS
    const int rfrag = (lane >> 4) * 4;   // D layout: col=lane&15, row=(lane>>4)*4+j
    #pragma unroll
    for (int mr = 0; mr < 4; ++mr) {
        #pragma unroll
        for (int j = 0; j < 4; ++j) {
            const int rr = wrow + mr * 16 + rfrag + j;
            #pragma unroll
            for (int nc = 0; nc < 4; ++nc)
                ftile[rr * BN + wcol + nc * 16 + fr] = fmaxf(acc[mr][nc][j], 0.0f);
        }
    }
    __syncthreads();

    // thread t: row r = t>>1 (0..127), d-range (t&1)*8..+7
    // column scan rotated by r to break the all-rows-same-bank pattern
    {
        const int r = t >> 1;
        const int d0 = (t & 1) * 8;
        float sum[8];
        #pragma unroll
        for (int i = 0; i < 8; ++i) sum[i] = 0.0f;
        for (int cc = 0; cc < BN; ++cc) {
            const int c = (cc + r) & (BN - 1);
            float hv = ftile[r * BN + c];
            const float4* w3p = (const float4*)&W3[(size_t)(n0 + c) * 16 + d0];
            float4 a = w3p[0], b = w3p[1];
            sum[0] = fmaf(hv, a.x, sum[0]); sum[1] = fmaf(hv, a.y, sum[1]);
            sum[2] = fmaf(hv, a.z, sum[2]); sum[3] = fmaf(hv, a.w, sum[3]);
            sum[4] = fmaf(hv, b.x, sum[4]); sum[5] = fmaf(hv, b.y, sum[5]);
            sum[6] = fmaf(hv, b.z, sum[6]); sum[7] = fmaf(hv, b.w, sum[7]);
        }
        float* orow = &out16[(size_t)(m0 + r) * 16 + d0];
        #pragma unroll
        for (int i = 0; i < 8; ++i) atomicAdd(&orow[i], sum[i]);
    }
}

// ---------------- layer C: epilogue + permute (reads tiny out16) ----------------
__global__ __launch_bounds__(256) void layerC_kernel(
    const float* __restrict__ out16, const float* __restrict__ b3,
    const float* __restrict__ armsrc, float* __restrict__ armdst,
    float* __restrict__ ldjws, const int* __restrict__ perm,
    float* __restrict__ outfinal, int layer, int chunk_start, int rows_c)
{
    const int row_l = blockIdx.x * 256 + threadIdx.x;
    if (row_l >= rows_c) return;
    const int row = chunk_start + row_l;

    float armRow[16];
    #pragma unroll
    for (int q = 0; q < 16; ++q) armRow[q] = armsrc[(size_t)row * D_SZ + q];

    float alt[8];
    float lsum = 0.0f;
    #pragma unroll
    for (int dd = 0; dd < 8; ++dd) {
        float sv = fminf(fmaxf(out16[(size_t)row_l * 16 + dd] + b3[dd], -10.0f), 10.0f);
        float tv = fminf(fmaxf(out16[(size_t)row_l * 16 + dd + 8] + b3[dd + 8], -10.0f), 10.0f);
        alt[dd] = armRow[dd + 8] * expf(sv) + tv;
        lsum += logf(fabsf(sv));
    }
    float lprev = (layer == 0) ? 0.0f : ldjws[row];
    float lnew = lprev + lsum * 0.125f;

    float nc[16];
    #pragma unroll
    for (int q = 0; q < 16; ++q) {
        int pi = perm[q];
        nc[q] = (pi < 8) ? armRow[pi] : alt[pi - 8];
    }
    if (layer == NLAYERS - 1) {
        #pragma unroll
        for (int q = 0; q < 16; ++q) outfinal[(size_t)row * D_SZ + q] = nc[q];
        outfinal[(size_t)B_SZ * D_SZ + row] = lnew;
    } else {
        #pragma unroll
        for (int q = 0; q < 16; ++q) armdst[(size_t)row * D_SZ + q] = nc[q];
        ldjws[row] = lnew;
    }
}

extern "C" void kernel_launch(void* const* d_in, const int* in_sizes, int n_in,
                              void* d_out, int out_size, void* d_ws, size_t ws_size,
                              hipStream_t stream) {
    const float* arm = (const float*)d_in[0];
    const float* cx  = (const float*)d_in[1];
    const float* cy  = (const float*)d_in[2];
    const float* cc  = (const float*)d_in[3];
    const float* W1  = (const float*)d_in[4];
    const float* b1  = (const float*)d_in[5];
    const float* W2  = (const float*)d_in[6];
    const float* b2  = (const float*)d_in[7];
    const float* W3  = (const float*)d_in[8];
    const float* b3  = (const float*)d_in[9];
    const int* seed  = (const int*)d_in[10];
    float* out = (float*)d_out;

    char* ws = (char*)d_ws;
    size_t cur = 0;
    auto alloc = [&](size_t bytes) {
        size_t off = cur;
        cur += (bytes + 255) & ~(size_t)255;
        return (void*)(ws + off);
    };
    // fixed allocations (~19 MB)
    int*   perm   = (int*)  alloc(64);
    float* arm_ws = (float*)alloc((size_t)B_SZ * D_SZ * 4);
    float* ldj_ws = (float*)alloc((size_t)B_SZ * 4);
    u16*   W2thi  = (u16*)  alloc((size_t)H_SZ * H_SZ * 2);
    u16*   W2tlo  = (u16*)  alloc((size_t)H_SZ * H_SZ * 2);

    // adaptive chunk: per-row cost = h1hi+h1lo (2048*2*2B) + out16 (64B) = 8256 B
    long chunk = B_SZ;
    {
        size_t fixed = cur + 4096;  // slack for alignment pads
        size_t avail = (ws_size > fixed) ? (ws_size - fixed) : 0;
        long c = (long)(avail / 8256);
        c = (c / 128) * 128;
        if (c < 128) c = 128;       // nothing smaller is possible; 128 needs ~20 MB total
        if (c > B_SZ) c = B_SZ;
        chunk = c;
    }
    u16*   h1hi  = (u16*)  alloc((size_t)chunk * H_SZ * 2);
    u16*   h1lo  = (u16*)  alloc((size_t)chunk * H_SZ * 2);
    float* out16 = (float*)alloc((size_t)chunk * 16 * 4);

    hipLaunchKernelGGL(perm_kernel, dim3(1), dim3(64), 0, stream, seed, perm);
    hipLaunchKernelGGL(presplit_kernel, dim3(4096), dim3(256), 0, stream, W2, W2thi, W2tlo);

    for (long cs = 0; cs < B_SZ; cs += chunk) {
        long rc = B_SZ - cs;
        if (rc > chunk) rc = chunk;          // always a multiple of 128
        for (int layer = 0; layer < NLAYERS; ++layer) {
            const float* asrc = (layer == 0) ? arm : arm_ws;
            hipLaunchKernelGGL(layerA_kernel, dim3(rc / 4), dim3(256), 0, stream,
                               asrc, cx, cy, cc, W1, b1, h1hi, h1lo, out16,
                               layer, (int)cs);
            hipLaunchKernelGGL(gemm_kernel, dim3((rc / BM) * (H_SZ / BN)), dim3(256), 0, stream,
                               h1hi, h1lo, W2thi, W2tlo, b2, W3, out16);
            hipLaunchKernelGGL(layerC_kernel, dim3((rc + 255) / 256), dim3(256), 0, stream,
                               out16, b3, asrc, arm_ws, ldj_ws, perm, out,
                               layer, (int)cs, (int)rc);
        }
    }
}